// Round 2
// baseline (1020.197 us; speedup 1.0000x reference)
//
#include <hip/hip_runtime.h>

typedef unsigned short u16;
typedef __attribute__((ext_vector_type(8))) short s8v;
typedef __attribute__((ext_vector_type(8))) __bf16 bf8;
typedef __attribute__((ext_vector_type(4))) float f4v;

#define GLB(p) ((const __attribute__((address_space(1))) void*)(p))
#define LDS(p) ((__attribute__((address_space(3))) void*)(p))

static __device__ __forceinline__ float b2f(u16 u) {
    union { unsigned int i; float f; } v; v.i = ((unsigned int)u) << 16; return v.f;
}
static __device__ __forceinline__ u16 f2b(float f) {
    union { float f; unsigned int i; } v; v.f = f;
    v.i += 0x7fffu + ((v.i >> 16) & 1u);   // RNE
    return (u16)(v.i >> 16);
}

// ---------------- f32 -> bf16 convert, 4 elems/thread ----------------
__global__ __launch_bounds__(256) void k_conv(const float* __restrict__ in,
                                              u16* __restrict__ out, int n4) {
    int i = blockIdx.x * 256 + threadIdx.x;
    if (i >= n4) return;
    float4 v = ((const float4*)in)[i];
    union { u16 u[4]; unsigned long long ll; } o;
    o.u[0] = f2b(v.x); o.u[1] = f2b(v.y); o.u[2] = f2b(v.z); o.u[3] = f2b(v.w);
    ((unsigned long long*)out)[i] = o.ll;
}

// ---------------- C = A(MxK) * B(NxK)^T, 128x128 tile, BK=32 ----------------
// MODE 0: scatter bf16 into Q/K head-major [bh][t][128], V TRANSPOSED [bh][128][t]
// MODE 1: write f32 row-major C (M x N)
template<int MODE>
__global__ __launch_bounds__(256) void k_gemm_bt(
    const u16* __restrict__ A, const u16* __restrict__ B,
    int K, int N,
    u16* __restrict__ Qb, u16* __restrict__ Kb, u16* __restrict__ Vt,
    float* __restrict__ Cf)
{
    __shared__ __align__(16) u16 As[128 * 32];
    __shared__ __align__(16) u16 Bs[128 * 32];
    const int tid = threadIdx.x;
    const int lane = tid & 63;
    const int wid = tid >> 6;
    const int wr = wid >> 1, wc = wid & 1;         // 2x2 wave grid, 64x64 each
    const long arow0 = (long)blockIdx.y * 128;
    const long brow0 = (long)blockIdx.x * 128;
    const int la = lane & 15, lb = lane >> 4;

    f4v acc[4][4];
#pragma unroll
    for (int m = 0; m < 4; m++)
#pragma unroll
        for (int n = 0; n < 4; n++) acc[m][n] = (f4v){0.f, 0.f, 0.f, 0.f};

    const u16* Ag = A + (arow0 + (tid >> 2)) * (long)K + (tid & 3) * 8;
    const u16* Bg = B + (brow0 + (tid >> 2)) * (long)K + (tid & 3) * 8;
    const int aoff = (wr * 64 + la) * 32 + lb * 8;
    const int boff = (wc * 64 + la) * 32 + lb * 8;

    const int kiters = K >> 5;
    for (int kt = 0; kt < kiters; ++kt) {
        __syncthreads();
        const u16* ag = Ag + kt * 32;
        const u16* bg = Bg + kt * 32;
        __builtin_amdgcn_global_load_lds(GLB(ag),                LDS(As + tid * 8),        16, 0, 0);
        __builtin_amdgcn_global_load_lds(GLB(ag + 64 * (long)K), LDS(As + 2048 + tid * 8), 16, 0, 0);
        __builtin_amdgcn_global_load_lds(GLB(bg),                LDS(Bs + tid * 8),        16, 0, 0);
        __builtin_amdgcn_global_load_lds(GLB(bg + 64 * (long)K), LDS(Bs + 2048 + tid * 8), 16, 0, 0);
        __syncthreads();
        bf8 af[4], bfv[4];
#pragma unroll
        for (int m = 0; m < 4; m++) af[m] = *(const bf8*)(As + aoff + m * 512);
#pragma unroll
        for (int n = 0; n < 4; n++) bfv[n] = *(const bf8*)(Bs + boff + n * 512);
#pragma unroll
        for (int m = 0; m < 4; m++)
#pragma unroll
            for (int n = 0; n < 4; n++)
                acc[m][n] = __builtin_amdgcn_mfma_f32_16x16x32_bf16(af[m], bfv[n], acc[m][n], 0, 0, 0);
    }

#pragma unroll
    for (int m = 0; m < 4; m++) {
#pragma unroll
        for (int n = 0; n < 4; n++) {
            const long grow0 = arow0 + wr * 64 + m * 16 + lb * 4;
            const int  gcol  = (int)brow0 + wc * 64 + n * 16 + la;
#pragma unroll
            for (int i = 0; i < 4; i++) {
                const float v = acc[m][n][i];
                const long r = grow0 + i;
                if (MODE == 0) {
                    const int part = gcol >> 11;           // 0=Q 1=K 2=V
                    const int rem  = gcol & 2047;
                    const int head = rem >> 7, d = rem & 127;
                    const long bh = (r >> 11) * 16 + head;
                    const int t = (int)(r & 2047);
                    if (part == 2) {
                        // V transposed: [bh][d][t]
                        Vt[(bh << 18) + ((long)d << 11) + t] = f2b(v);
                    } else {
                        u16* dst = (part == 0) ? Qb : Kb;
                        dst[((bh << 11) + t) * 128 + d] = f2b(v);
                    }
                } else {
                    Cf[r * (long)N + gcol] = v;
                }
            }
        }
    }
}

// ---------------- RoPE in place on Q and K (head-major) ----------------
__global__ __launch_bounds__(256) void k_rope(u16* __restrict__ Qb, u16* __restrict__ Kb,
                                              const int* __restrict__ pos) {
    const int idx = blockIdx.x * 256 + threadIdx.x;   // 2 * 64 * 2048 * 64 threads
    const int j  = idx & 63;
    const int t  = (idx >> 6) & 2047;
    const int bh = (idx >> 17) & 63;
    u16* P = (idx >> 23) ? Kb : Qb;
    const long off = ((((long)bh << 11) + t) << 7) + 2 * j;
    unsigned int raw = *(unsigned int*)(P + off);
    float x1 = b2f((u16)(raw & 0xffffu));
    float x2 = b2f((u16)(raw >> 16));
    float invf = exp2f((float)j * -0.20762050593046014f);  // 10000^(-j/64)
    float ang = (float)pos[t] * invf;
    float sn, cs;
    sincosf(ang, &sn, &cs);
    unsigned int o = (unsigned int)f2b(x1 * cs - x2 * sn)
                   | ((unsigned int)f2b(x1 * sn + x2 * cs) << 16);
    *(unsigned int*)(P + off) = o;
}

// ---------------- causal flash attention ----------------
// 256 threads = 4 independent waves; wave w handles q-tile qt = (gridDim.x-1-bid)*4 + w
// (reverse order: longest causal rows dispatch first). V is pre-transposed [bh][d][t]
// so the PV B-fragment is a single contiguous 16B load.
__global__ __launch_bounds__(256) void k_attn(const u16* __restrict__ Qb,
                                              const u16* __restrict__ Kb,
                                              const u16* __restrict__ Vt,
                                              u16* __restrict__ Ob)
{
    __shared__ __align__(16) u16 Pl[4][32 * 32];
    const int tid = threadIdx.x;
    const int lane = tid & 63;
    const int w = tid >> 6;
    const int la = lane & 15, lb = lane >> 4;
    const int qt = ((int)gridDim.x - 1 - (int)blockIdx.x) * 4 + w;
    const int bh = blockIdx.y;
    const long base = (long)bh << 18;          // bh * 2048 * 128
    const int q0 = qt * 32;
    const float scale = 0.08838834764831845f;  // 1/sqrt(128)

    bf8 qf[2][4];
#pragma unroll
    for (int m = 0; m < 2; m++)
#pragma unroll
        for (int kb = 0; kb < 4; kb++)
            qf[m][kb] = *(const bf8*)(Qb + base + (long)(q0 + m * 16 + la) * 128 + kb * 32 + lb * 8);

    f4v o[2][8];
#pragma unroll
    for (int m = 0; m < 2; m++)
#pragma unroll
        for (int n = 0; n < 8; n++) o[m][n] = (f4v){0.f, 0.f, 0.f, 0.f};
    float mst[2][4], lst[2][4];
#pragma unroll
    for (int m = 0; m < 2; m++)
#pragma unroll
        for (int i = 0; i < 4; i++) { mst[m][i] = -1e30f; lst[m][i] = 0.f; }

    char* Pb = (char*)(Pl[w]);

    for (int jt = 0; jt <= qt; ++jt) {
        const int kv0 = jt * 32;
        f4v s[2][2];
        s[0][0] = s[0][1] = s[1][0] = s[1][1] = (f4v){0.f, 0.f, 0.f, 0.f};
#pragma unroll
        for (int n = 0; n < 2; n++) {
#pragma unroll
            for (int kb = 0; kb < 4; kb++) {
                bf8 kf = *(const bf8*)(Kb + base + (long)(kv0 + n * 16 + la) * 128 + kb * 32 + lb * 8);
                s[0][n] = __builtin_amdgcn_mfma_f32_16x16x32_bf16(qf[0][kb], kf, s[0][n], 0, 0, 0);
                s[1][n] = __builtin_amdgcn_mfma_f32_16x16x32_bf16(qf[1][kb], kf, s[1][n], 0, 0, 0);
            }
        }
        // V fragments are independent of softmax — issue loads now, consume after.
        bf8 vf[8];
#pragma unroll
        for (int nO = 0; nO < 8; nO++)
            vf[nO] = *(const bf8*)(Vt + base + (long)(nO * 16 + la) * 2048 + kv0 + lb * 8);

        float p[2][2][4];
        const bool diag = (jt == qt);
#pragma unroll
        for (int m = 0; m < 2; m++)
#pragma unroll
            for (int n = 0; n < 2; n++)
#pragma unroll
                for (int i = 0; i < 4; i++) {
                    float v = s[m][n][i] * scale;
                    if (diag && (n * 16 + la) > (m * 16 + lb * 4 + i)) v = -1e30f;
                    p[m][n][i] = v;
                }
        float corr[2][4];
#pragma unroll
        for (int m = 0; m < 2; m++)
#pragma unroll
            for (int i = 0; i < 4; i++) {
                float r = fmaxf(p[m][0][i], p[m][1][i]);
                r = fmaxf(r, __shfl_xor(r, 1));
                r = fmaxf(r, __shfl_xor(r, 2));
                r = fmaxf(r, __shfl_xor(r, 4));
                r = fmaxf(r, __shfl_xor(r, 8));
                const float mnew = fmaxf(mst[m][i], r);
                const float c = __expf(mst[m][i] - mnew);
                mst[m][i] = mnew;
                corr[m][i] = c;
                float sum = 0.f;
#pragma unroll
                for (int n = 0; n < 2; n++) {
                    p[m][n][i] = __expf(p[m][n][i] - mnew);
                    sum += p[m][n][i];
                }
                sum += __shfl_xor(sum, 1);
                sum += __shfl_xor(sum, 2);
                sum += __shfl_xor(sum, 4);
                sum += __shfl_xor(sum, 8);
                lst[m][i] = lst[m][i] * c + sum;
            }
#pragma unroll
        for (int m = 0; m < 2; m++)
#pragma unroll
            for (int n = 0; n < 8; n++)
#pragma unroll
                for (int i = 0; i < 4; i++) o[m][n][i] *= corr[m][i];

        // P -> LDS (per-wave buffer; same-wave DS ordering, no barrier needed)
#pragma unroll
        for (int m = 0; m < 2; m++)
#pragma unroll
            for (int n = 0; n < 2; n++)
#pragma unroll
                for (int i = 0; i < 4; i++) {
                    const int row = m * 16 + lb * 4 + i;
                    const int colb = (n * 16 + la) * 2;
                    *(u16*)(Pb + row * 64 + (colb ^ ((row & 3) << 4))) = f2b(p[m][n][i]);
                }
        bf8 pa[2];
#pragma unroll
        for (int am = 0; am < 2; am++) {
            const int row = am * 16 + la;
            pa[am] = *(const bf8*)(Pb + row * 64 + ((lb * 16) ^ ((row & 3) << 4)));
        }
#pragma unroll
        for (int nO = 0; nO < 8; nO++) {
            o[0][nO] = __builtin_amdgcn_mfma_f32_16x16x32_bf16(pa[0], vf[nO], o[0][nO], 0, 0, 0);
            o[1][nO] = __builtin_amdgcn_mfma_f32_16x16x32_bf16(pa[1], vf[nO], o[1][nO], 0, 0, 0);
        }
    }

    const int b = bh >> 4, h = bh & 15;
#pragma unroll
    for (int m = 0; m < 2; m++)
#pragma unroll
        for (int nO = 0; nO < 8; nO++)
#pragma unroll
            for (int i = 0; i < 4; i++) {
                const int row = q0 + m * 16 + lb * 4 + i;
                const int d = nO * 16 + la;
                Ob[((long)(b * 2048 + row) << 11) + h * 128 + d] = f2b(o[m][nO][i] / lst[m][i]);
            }
}

extern "C" void kernel_launch(void* const* d_in, const int* in_sizes, int n_in,
                              void* d_out, int out_size, void* d_ws, size_t ws_size,
                              hipStream_t stream)
{
    const float* X    = (const float*)d_in[0];
    const int*   pos  = (const int*)d_in[1];
    const float* Wqkv = (const float*)d_in[2];
    const float* Wo   = (const float*)d_in[3];
    float* out = (float*)d_out;

    char* ws = (char*)d_ws;
    u16* Xb    = (u16*)(ws + 0);          // 8192x2048 bf16   (32 MiB)
    u16* Wqkvb = (u16*)(ws + 33554432);   // 6144x2048 bf16   (24 MiB)
    u16* Wob   = (u16*)(ws + 58720256);   // 2048x2048 bf16   ( 8 MiB)
    u16* Qb    = (u16*)(ws + 67108864);   // [bh][t][128] bf16 (32 MiB)
    u16* Kb    = (u16*)(ws + 100663296);  // [bh][t][128]
    u16* Vt    = (u16*)(ws + 134217728);  // [bh][128][t]  (transposed)
    u16* Ob    = (u16*)(ws + 167772160);  // [b][t][2048] bf16

    k_conv<<<16384, 256, 0, stream>>>(X, Xb, 4194304);
    k_conv<<<12288, 256, 0, stream>>>(Wqkv, Wqkvb, 3145728);
    k_conv<<<4096, 256, 0, stream>>>(Wo, Wob, 1048576);
    k_gemm_bt<0><<<dim3(48, 64), 256, 0, stream>>>(Xb, Wqkvb, 2048, 6144, Qb, Kb, Vt, nullptr);
    k_rope<<<65536, 256, 0, stream>>>(Qb, Kb, pos);
    k_attn<<<dim3(16, 64), 256, 0, stream>>>(Qb, Kb, Vt, Ob);
    k_gemm_bt<1><<<dim3(16, 64), 256, 0, stream>>>(Ob, Wob, 2048, 2048, nullptr, nullptr, nullptr, out);
}

// Round 3
// 599.215 us; speedup vs baseline: 1.7026x; 1.7026x over previous
//
#include <hip/hip_runtime.h>

typedef unsigned short u16;
typedef __attribute__((ext_vector_type(8))) short s8v;
typedef __attribute__((ext_vector_type(8))) __bf16 bf8;
typedef __attribute__((ext_vector_type(4))) float f4v;

#define GLB(p) ((const __attribute__((address_space(1))) void*)(p))
#define LDS(p) ((__attribute__((address_space(3))) void*)(p))

static __device__ __forceinline__ float b2f(u16 u) {
    union { unsigned int i; float f; } v; v.i = ((unsigned int)u) << 16; return v.f;
}
static __device__ __forceinline__ u16 f2b(float f) {
    union { float f; unsigned int i; } v; v.f = f;
    v.i += 0x7fffu + ((v.i >> 16) & 1u);   // RNE
    return (u16)(v.i >> 16);
}

// ---------------- f32 -> bf16 convert, 4 elems/thread ----------------
__global__ __launch_bounds__(256) void k_conv(const float* __restrict__ in,
                                              u16* __restrict__ out, int n4) {
    int i = blockIdx.x * 256 + threadIdx.x;
    if (i >= n4) return;
    float4 v = ((const float4*)in)[i];
    union { u16 u[4]; unsigned long long ll; } o;
    o.u[0] = f2b(v.x); o.u[1] = f2b(v.y); o.u[2] = f2b(v.z); o.u[3] = f2b(v.w);
    ((unsigned long long*)out)[i] = o.ll;
}

// ---------------- C = A(MxK) * B(NxK)^T, 128x128 tile, BK=32 ----------------
// MODE 0: scatter bf16 into Q/K head-major [bh][t][128], V TRANSPOSED [bh][128][t]
// MODE 1: write f32 row-major C (M x N)
template<int MODE>
__global__ __launch_bounds__(256) void k_gemm_bt(
    const u16* __restrict__ A, const u16* __restrict__ B,
    int K, int N,
    u16* __restrict__ Qb, u16* __restrict__ Kb, u16* __restrict__ Vt,
    float* __restrict__ Cf)
{
    __shared__ __align__(16) u16 As[128 * 32];
    __shared__ __align__(16) u16 Bs[128 * 32];
    const int tid = threadIdx.x;
    const int lane = tid & 63;
    const int wid = tid >> 6;
    const int wr = wid >> 1, wc = wid & 1;         // 2x2 wave grid, 64x64 each
    const long arow0 = (long)blockIdx.y * 128;
    const long brow0 = (long)blockIdx.x * 128;
    const int la = lane & 15, lb = lane >> 4;

    f4v acc[4][4];
#pragma unroll
    for (int m = 0; m < 4; m++)
#pragma unroll
        for (int n = 0; n < 4; n++) acc[m][n] = (f4v){0.f, 0.f, 0.f, 0.f};

    const u16* Ag = A + (arow0 + (tid >> 2)) * (long)K + (tid & 3) * 8;
    const u16* Bg = B + (brow0 + (tid >> 2)) * (long)K + (tid & 3) * 8;
    const int aoff = (wr * 64 + la) * 32 + lb * 8;
    const int boff = (wc * 64 + la) * 32 + lb * 8;

    const int kiters = K >> 5;
    for (int kt = 0; kt < kiters; ++kt) {
        __syncthreads();
        const u16* ag = Ag + kt * 32;
        const u16* bg = Bg + kt * 32;
        __builtin_amdgcn_global_load_lds(GLB(ag),                LDS(As + tid * 8),        16, 0, 0);
        __builtin_amdgcn_global_load_lds(GLB(ag + 64 * (long)K), LDS(As + 2048 + tid * 8), 16, 0, 0);
        __builtin_amdgcn_global_load_lds(GLB(bg),                LDS(Bs + tid * 8),        16, 0, 0);
        __builtin_amdgcn_global_load_lds(GLB(bg + 64 * (long)K), LDS(Bs + 2048 + tid * 8), 16, 0, 0);
        __syncthreads();
        bf8 af[4], bfv[4];
#pragma unroll
        for (int m = 0; m < 4; m++) af[m] = *(const bf8*)(As + aoff + m * 512);
#pragma unroll
        for (int n = 0; n < 4; n++) bfv[n] = *(const bf8*)(Bs + boff + n * 512);
#pragma unroll
        for (int m = 0; m < 4; m++)
#pragma unroll
            for (int n = 0; n < 4; n++)
                acc[m][n] = __builtin_amdgcn_mfma_f32_16x16x32_bf16(af[m], bfv[n], acc[m][n], 0, 0, 0);
    }

#pragma unroll
    for (int m = 0; m < 4; m++) {
#pragma unroll
        for (int n = 0; n < 4; n++) {
            const long grow0 = arow0 + wr * 64 + m * 16 + lb * 4;
            const int  gcol  = (int)brow0 + wc * 64 + n * 16 + la;
#pragma unroll
            for (int i = 0; i < 4; i++) {
                const float v = acc[m][n][i];
                const long r = grow0 + i;
                if (MODE == 0) {
                    const int part = gcol >> 11;           // 0=Q 1=K 2=V
                    const int rem  = gcol & 2047;
                    const int head = rem >> 7, d = rem & 127;
                    const long bh = (r >> 11) * 16 + head;
                    const int t = (int)(r & 2047);
                    if (part == 2) {
                        Vt[(bh << 18) + ((long)d << 11) + t] = f2b(v);   // [bh][d][t]
                    } else {
                        u16* dst = (part == 0) ? Qb : Kb;
                        dst[((bh << 11) + t) * 128 + d] = f2b(v);
                    }
                } else {
                    Cf[r * (long)N + gcol] = v;
                }
            }
        }
    }
}

// ---------------- RoPE in place on Q and K (head-major) ----------------
__global__ __launch_bounds__(256) void k_rope(u16* __restrict__ Qb, u16* __restrict__ Kb,
                                              const int* __restrict__ pos) {
    const int idx = blockIdx.x * 256 + threadIdx.x;   // 2 * 64 * 2048 * 64 threads
    const int j  = idx & 63;
    const int t  = (idx >> 6) & 2047;
    const int bh = (idx >> 17) & 63;
    u16* P = (idx >> 23) ? Kb : Qb;
    const long off = ((((long)bh << 11) + t) << 7) + 2 * j;
    unsigned int raw = *(unsigned int*)(P + off);
    float x1 = b2f((u16)(raw & 0xffffu));
    float x2 = b2f((u16)(raw >> 16));
    float invf = exp2f((float)j * -0.20762050593046014f);  // 10000^(-j/64)
    float ang = (float)pos[t] * invf;
    float sn, cs;
    sincosf(ang, &sn, &cs);
    unsigned int o = (unsigned int)f2b(x1 * cs - x2 * sn)
                   | ((unsigned int)f2b(x1 * sn + x2 * cs) << 16);
    *(unsigned int*)(P + off) = o;
}

// ---------------- causal flash attention, block-cooperative ----------------
// 512 threads = 8 waves; block covers 8 q-tiles (256 q-rows) of one bh.
// K/V tiles (32 kv rows) staged in double-buffered, XOR-swizzled LDS shared by
// all 8 waves. Fixed-max softmax p=exp(s-8): no per-iteration cross-lane ops;
// denominator reduced once at the end. Blocks dispatched longest-first (LPT).
__global__ __launch_bounds__(512) void k_attn(const u16* __restrict__ Qb,
                                              const u16* __restrict__ Kb,
                                              const u16* __restrict__ Vt,
                                              u16* __restrict__ Ob)
{
    __shared__ __align__(16) u16 Ks[2][32 * 128];   // 2 x 8KB, swizzled rows of 256B
    __shared__ __align__(16) u16 Vs[2][64 * 64];    // 2 x 8KB, row R = d-pair, 128B rows
    __shared__ __align__(16) u16 Pl[8][32 * 32];    // per-wave P buffer, 2KB each

    const int tid  = threadIdx.x;
    const int lane = tid & 63;
    const int w    = tid >> 6;
    const int la = lane & 15, lb = lane >> 4;
    const int qg = 7 - ((int)blockIdx.x >> 6);      // longest blocks dispatch first
    const int bh = blockIdx.x & 63;
    const long base = (long)bh << 18;               // bh * 2048 * 128
    const int qt = qg * 8 + w;
    const int q0 = qt * 32;
    const int tiles_w = qt + 1;                     // kv tiles (32-wide) incl. diagonal
    const int NT = qg * 8 + 8;                      // block max tiles
    const float scale = 0.08838834764831845f;       // 1/sqrt(128)

    // Q fragments in registers (post-RoPE)
    bf8 qf[2][4];
#pragma unroll
    for (int m = 0; m < 2; m++)
#pragma unroll
        for (int kb = 0; kb < 4; kb++)
            qf[m][kb] = *(const bf8*)(Qb + base + (long)(q0 + m * 16 + la) * 128 + kb * 32 + lb * 8);

    f4v o[2][8];
#pragma unroll
    for (int m = 0; m < 2; m++)
#pragma unroll
        for (int n = 0; n < 8; n++) o[m][n] = (f4v){0.f, 0.f, 0.f, 0.f};
    float lst[2][4];
#pragma unroll
    for (int m = 0; m < 2; m++)
#pragma unroll
        for (int i = 0; i < 4; i++) lst[m][i] = 0.f;

    char* Pb = (char*)(Pl[w]);

    // ---- staging: LDS linear dest, inverse-swizzled global source ----
    // K tile: LDS[r*256 + c'] holds K[kv0+r][ (c'^((r&7)<<4)) /2 .. ]
    // V tile: LDS[R*128 + c'] with c = c'^((R&7)<<4): d=2R+(c>=64), t=kv0+(c&63)/2
    const int ko = tid * 16;
    const int kr = ko >> 8, kc = (ko & 255) ^ ((kr & 7) << 4);
    const int vo = tid * 16;
    const int vR = vo >> 7, vc = (vo & 127) ^ ((vR & 7) << 4);
    const int vd = 2 * vR + (vc >> 6), vt = (vc & 63) >> 1;

#define STAGE(buf, jt_) do {                                                        \
        const int kv0_ = (jt_) * 32;                                               \
        __builtin_amdgcn_global_load_lds(                                          \
            GLB(Kb + base + (long)(kv0_ + kr) * 128 + (kc >> 1)),                  \
            LDS((u16*)Ks[buf] + tid * 8), 16, 0, 0);                               \
        __builtin_amdgcn_global_load_lds(                                          \
            GLB(Vt + base + ((long)vd << 11) + kv0_ + vt),                         \
            LDS((u16*)Vs[buf] + tid * 8), 16, 0, 0);                               \
    } while (0)

    STAGE(0, 0);

    for (int jt = 0; jt < NT; ++jt) {
        const int buf = jt & 1;
        __syncthreads();                       // drains vmcnt: buf ready
        if (jt + 1 < NT) STAGE(buf ^ 1, jt + 1);

        if (jt < tiles_w) {
            const char* KsB = (const char*)Ks[buf];
            const char* VsB = (const char*)Vs[buf];

            // QK^T from LDS (swizzled reads)
            f4v s[2][2];
            s[0][0] = s[0][1] = s[1][0] = s[1][1] = (f4v){0.f, 0.f, 0.f, 0.f};
#pragma unroll
            for (int n = 0; n < 2; n++) {
                const int row = n * 16 + la;
#pragma unroll
                for (int kb = 0; kb < 4; kb++) {
                    bf8 kf = *(const bf8*)(KsB + row * 256 + ((kb * 64 + lb * 16) ^ ((row & 7) << 4)));
                    s[0][n] = __builtin_amdgcn_mfma_f32_16x16x32_bf16(qf[0][kb], kf, s[0][n], 0, 0, 0);
                    s[1][n] = __builtin_amdgcn_mfma_f32_16x16x32_bf16(qf[1][kb], kf, s[1][n], 0, 0, 0);
                }
            }

            // V fragments from LDS (independent of softmax)
            bf8 vf[8];
#pragma unroll
            for (int nO = 0; nO < 8; nO++) {
                const int R = nO * 8 + (la >> 1);
                vf[nO] = *(const bf8*)(VsB + R * 128 + (((la & 1) * 64 + lb * 16) ^ ((R & 7) << 4)));
            }

            // fixed-max softmax: p = exp(s*scale - 8); masked -> 0.
            const bool diag = (jt == qt);
            float p[2][2][4];
#pragma unroll
            for (int m = 0; m < 2; m++)
#pragma unroll
                for (int n = 0; n < 2; n++)
#pragma unroll
                    for (int i = 0; i < 4; i++) {
                        float v = __expf(fmaf(s[m][n][i], scale, -8.0f));
                        if (diag && (n * 16 + la) > (m * 16 + lb * 4 + i)) v = 0.f;
                        p[m][n][i] = v;
                        lst[m][i] += v;
                    }

            // P -> per-wave LDS (swizzled), re-fragment as MFMA A-operand
#pragma unroll
            for (int m = 0; m < 2; m++)
#pragma unroll
                for (int n = 0; n < 2; n++)
#pragma unroll
                    for (int i = 0; i < 4; i++) {
                        const int row = m * 16 + lb * 4 + i;
                        const int colb = (n * 16 + la) * 2;
                        *(u16*)(Pb + row * 64 + (colb ^ ((row & 3) << 4))) = f2b(p[m][n][i]);
                    }
            bf8 pa[2];
#pragma unroll
            for (int am = 0; am < 2; am++) {
                const int row = am * 16 + la;
                pa[am] = *(const bf8*)(Pb + row * 64 + ((lb * 16) ^ ((row & 3) << 4)));
            }
#pragma unroll
            for (int nO = 0; nO < 8; nO++) {
                o[0][nO] = __builtin_amdgcn_mfma_f32_16x16x32_bf16(pa[0], vf[nO], o[0][nO], 0, 0, 0);
                o[1][nO] = __builtin_amdgcn_mfma_f32_16x16x32_bf16(pa[1], vf[nO], o[1][nO], 0, 0, 0);
            }
        }
        __syncthreads();                       // all reads of buf done before overwrite
    }
#undef STAGE

    // final denominator reduce (once per kernel) + output
    float linv[2][4];
#pragma unroll
    for (int m = 0; m < 2; m++)
#pragma unroll
        for (int i = 0; i < 4; i++) {
            float l = lst[m][i];
            l += __shfl_xor(l, 1);
            l += __shfl_xor(l, 2);
            l += __shfl_xor(l, 4);
            l += __shfl_xor(l, 8);
            linv[m][i] = 1.0f / l;
        }

    const int b = bh >> 4, h = bh & 15;
#pragma unroll
    for (int m = 0; m < 2; m++)
#pragma unroll
        for (int nO = 0; nO < 8; nO++)
#pragma unroll
            for (int i = 0; i < 4; i++) {
                const int row = q0 + m * 16 + lb * 4 + i;
                const int d = nO * 16 + la;
                Ob[((long)(b * 2048 + row) << 11) + h * 128 + d] = f2b(o[m][nO][i] * linv[m][i]);
            }
}

extern "C" void kernel_launch(void* const* d_in, const int* in_sizes, int n_in,
                              void* d_out, int out_size, void* d_ws, size_t ws_size,
                              hipStream_t stream)
{
    const float* X    = (const float*)d_in[0];
    const int*   pos  = (const int*)d_in[1];
    const float* Wqkv = (const float*)d_in[2];
    const float* Wo   = (const float*)d_in[3];
    float* out = (float*)d_out;

    char* ws = (char*)d_ws;
    u16* Xb    = (u16*)(ws + 0);          // 8192x2048 bf16   (32 MiB)
    u16* Wqkvb = (u16*)(ws + 33554432);   // 6144x2048 bf16   (24 MiB)
    u16* Wob   = (u16*)(ws + 58720256);   // 2048x2048 bf16   ( 8 MiB)
    u16* Qb    = (u16*)(ws + 67108864);   // [bh][t][128] bf16 (32 MiB)
    u16* Kb    = (u16*)(ws + 100663296);  // [bh][t][128]
    u16* Vt    = (u16*)(ws + 134217728);  // [bh][128][t]  (transposed)
    u16* Ob    = (u16*)(ws + 167772160);  // [b][t][2048] bf16

    k_conv<<<16384, 256, 0, stream>>>(X, Xb, 4194304);
    k_conv<<<12288, 256, 0, stream>>>(Wqkv, Wqkvb, 3145728);
    k_conv<<<4096, 256, 0, stream>>>(Wo, Wob, 1048576);
    k_gemm_bt<0><<<dim3(48, 64), 256, 0, stream>>>(Xb, Wqkvb, 2048, 6144, Qb, Kb, Vt, nullptr);
    k_rope<<<65536, 256, 0, stream>>>(Qb, Kb, pos);
    k_attn<<<512, 512, 0, stream>>>(Qb, Kb, Vt, Ob);
    k_gemm_bt<1><<<dim3(16, 64), 256, 0, stream>>>(Ob, Wob, 2048, 2048, nullptr, nullptr, nullptr, out);
}

// Round 4
// 486.976 us; speedup vs baseline: 2.0950x; 1.2305x over previous
//
#include <hip/hip_runtime.h>

typedef unsigned short u16;
typedef __attribute__((ext_vector_type(8))) short s8v;
typedef __attribute__((ext_vector_type(8))) __bf16 bf8;
typedef __attribute__((ext_vector_type(4))) float f4v;

#define GLB(p) ((const __attribute__((address_space(1))) void*)(p))
#define LDS(p) ((__attribute__((address_space(3))) void*)(p))

static __device__ __forceinline__ float b2f(u16 u) {
    union { unsigned int i; float f; } v; v.i = ((unsigned int)u) << 16; return v.f;
}
static __device__ __forceinline__ u16 f2b(float f) {
    union { float f; unsigned int i; } v; v.f = f;
    v.i += 0x7fffu + ((v.i >> 16) & 1u);   // RNE
    return (u16)(v.i >> 16);
}

// ---------------- f32 -> bf16 convert, 4 elems/thread ----------------
__global__ __launch_bounds__(256) void k_conv(const float* __restrict__ in,
                                              u16* __restrict__ out, int n4) {
    int i = blockIdx.x * 256 + threadIdx.x;
    if (i >= n4) return;
    float4 v = ((const float4*)in)[i];
    union { u16 u[4]; unsigned long long ll; } o;
    o.u[0] = f2b(v.x); o.u[1] = f2b(v.y); o.u[2] = f2b(v.z); o.u[3] = f2b(v.w);
    ((unsigned long long*)out)[i] = o.ll;
}

// ============ C = A(MxK) * B(NxK)^T, 256x256 tile, BK=32, 8 waves ============
// 4-deep LDS ring (128 KB), staging 3 K-tiles ahead, counted vmcnt(8) + raw
// s_barrier per K-tile (never drain-0 in loop). XOR-swizzled LDS (col ^=
// ((row>>1)&3)<<4) with inverse swizzle on the global_load_lds SOURCE.
// MODE 0: scatter bf16 into Q/K head-major [bh][t][128], V transposed [bh][128][t]
// MODE 1: write f32 row-major C (M x N)
template<int MODE>
__global__ __launch_bounds__(512, 2) void k_gemm_bt(
    const u16* __restrict__ A, const u16* __restrict__ B,
    int K, int N, int gx,
    u16* __restrict__ Qb, u16* __restrict__ Kb, u16* __restrict__ Vt,
    float* __restrict__ Cf)
{
    extern __shared__ __align__(16) u16 Ls[];   // 4 bufs x (A 16KB + B 16KB) = 128 KB

    const int t    = threadIdx.x;
    const int lane = t & 63;
    const int wid  = t >> 6;
    const int wm = wid >> 2, wn = wid & 3;       // 2x4 wave grid; per-wave 128x64 out
    const int la = lane & 15, lb = lane >> 4;

    // XCD-bijective block swizzle (grid % 8 == 0)
    const int bid = (int)blockIdx.x;
    const int id2 = (bid & 7) * ((int)gridDim.x >> 3) + (bid >> 3);
    const int bx = id2 % gx, by = id2 / gx;
    const long arow0 = (long)by * 256;
    const long brow0 = (long)bx * 256;

    // ---- staging geometry: linear LDS dest, inverse-swizzled global source ----
    const int srow = t >> 2;                                    // 0..127
    const int scol = ((((t & 3) * 16) ^ (((t >> 3) & 3) << 4)) >> 1); // bf16 units
    const u16* Asrc = A + (arow0 + srow) * (long)K + scol;
    const u16* Bsrc = B + (brow0 + srow) * (long)K + scol;
    const long rK128 = (long)128 * K;

#define STAGE(q_, js_) do {                                                     \
        const long ko_ = (long)(js_) * 32;                                      \
        u16* Lq_ = Ls + (q_) * 16384;                                           \
        __builtin_amdgcn_global_load_lds(GLB(Asrc + ko_),         LDS(Lq_ + t * 8),         16, 0, 0); \
        __builtin_amdgcn_global_load_lds(GLB(Asrc + rK128 + ko_), LDS(Lq_ + 4096 + t * 8),  16, 0, 0); \
        __builtin_amdgcn_global_load_lds(GLB(Bsrc + ko_),         LDS(Lq_ + 8192 + t * 8),  16, 0, 0); \
        __builtin_amdgcn_global_load_lds(GLB(Bsrc + rK128 + ko_), LDS(Lq_ + 12288 + t * 8), 16, 0, 0); \
    } while (0)

    f4v acc[8][4];
#pragma unroll
    for (int m = 0; m < 8; m++)
#pragma unroll
        for (int n = 0; n < 4; n++) acc[m][n] = (f4v){0.f, 0.f, 0.f, 0.f};

    const int NKT = K >> 5;
    // prologue: prime 3 K-tiles; vmcnt(8) -> tile 0 (oldest 4 loads) landed
    STAGE(0, 0);
    STAGE(1, 1);
    STAGE(2, 2);
    asm volatile("s_waitcnt vmcnt(8)\n\ts_barrier" ::: "memory");

    // lane-constant swizzled fragment column (u16 units)
    const int fsw = (((lb * 16) ^ (((la >> 1) & 3) << 4)) >> 1);

    for (int jt = 0; jt < NKT; ++jt) {
        int js = jt + 3; if (js > NKT - 1) js = NKT - 1;   // idempotent tail restage
        STAGE(js & 3, js);

        const u16* Ac = Ls + (jt & 3) * 16384;
        const u16* Bc = Ac + 8192;
        bf8 af[8], bfr[4];
#pragma unroll
        for (int mi = 0; mi < 8; mi++)
            af[mi] = *(const bf8*)(Ac + (wm * 128 + mi * 16 + la) * 32 + fsw);
#pragma unroll
        for (int ni = 0; ni < 4; ni++)
            bfr[ni] = *(const bf8*)(Bc + (wn * 64 + ni * 16 + la) * 32 + fsw);

        __builtin_amdgcn_s_setprio(1);
#pragma unroll
        for (int mi = 0; mi < 8; mi++)
#pragma unroll
            for (int ni = 0; ni < 4; ni++)
                acc[mi][ni] = __builtin_amdgcn_mfma_f32_16x16x32_bf16(af[mi], bfr[ni], acc[mi][ni], 0, 0, 0);
        __builtin_amdgcn_s_setprio(0);

        // tile jt+1 guaranteed landed: only tiles jt+2, jt+3 (8 loads) may remain
        asm volatile("s_waitcnt vmcnt(8)\n\ts_barrier" ::: "memory");
    }
#undef STAGE
    asm volatile("s_waitcnt vmcnt(0)" ::: "memory");

#pragma unroll
    for (int mi = 0; mi < 8; mi++) {
#pragma unroll
        for (int ni = 0; ni < 4; ni++) {
            const long grow0 = arow0 + wm * 128 + mi * 16 + lb * 4;
            const int  gcol  = (int)brow0 + wn * 64 + ni * 16 + la;
#pragma unroll
            for (int i = 0; i < 4; i++) {
                const float v = acc[mi][ni][i];
                const long r = grow0 + i;
                if (MODE == 0) {
                    const int part = gcol >> 11;           // 0=Q 1=K 2=V
                    const int rem  = gcol & 2047;
                    const int head = rem >> 7, d = rem & 127;
                    const long bh = (r >> 11) * 16 + head;
                    const int tt = (int)(r & 2047);
                    if (part == 2) {
                        Vt[(bh << 18) + ((long)d << 11) + tt] = f2b(v);   // [bh][d][t]
                    } else {
                        u16* dst = (part == 0) ? Qb : Kb;
                        dst[((bh << 11) + tt) * 128 + d] = f2b(v);
                    }
                } else {
                    Cf[r * (long)N + gcol] = v;
                }
            }
        }
    }
}

// ---------------- RoPE in place on Q and K (head-major) ----------------
__global__ __launch_bounds__(256) void k_rope(u16* __restrict__ Qb, u16* __restrict__ Kb,
                                              const int* __restrict__ pos) {
    const int idx = blockIdx.x * 256 + threadIdx.x;   // 2 * 64 * 2048 * 64 threads
    const int j  = idx & 63;
    const int t  = (idx >> 6) & 2047;
    const int bh = (idx >> 17) & 63;
    u16* P = (idx >> 23) ? Kb : Qb;
    const long off = ((((long)bh << 11) + t) << 7) + 2 * j;
    unsigned int raw = *(unsigned int*)(P + off);
    float x1 = b2f((u16)(raw & 0xffffu));
    float x2 = b2f((u16)(raw >> 16));
    float invf = exp2f((float)j * -0.20762050593046014f);  // 10000^(-j/64)
    float ang = (float)pos[t] * invf;
    float sn, cs;
    sincosf(ang, &sn, &cs);
    unsigned int o = (unsigned int)f2b(x1 * cs - x2 * sn)
                   | ((unsigned int)f2b(x1 * sn + x2 * cs) << 16);
    *(unsigned int*)(P + off) = o;
}

// ---------------- causal flash attention, block-cooperative ----------------
__global__ __launch_bounds__(512) void k_attn(const u16* __restrict__ Qb,
                                              const u16* __restrict__ Kb,
                                              const u16* __restrict__ Vt,
                                              u16* __restrict__ Ob)
{
    __shared__ __align__(16) u16 Ks[2][32 * 128];   // 2 x 8KB, swizzled rows of 256B
    __shared__ __align__(16) u16 Vs[2][64 * 64];    // 2 x 8KB, row R = d-pair, 128B rows
    __shared__ __align__(16) u16 Pl[8][32 * 32];    // per-wave P buffer, 2KB each

    const int tid  = threadIdx.x;
    const int lane = tid & 63;
    const int w    = tid >> 6;
    const int la = lane & 15, lb = lane >> 4;
    const int qg = 7 - ((int)blockIdx.x >> 6);      // longest blocks dispatch first
    const int bh = blockIdx.x & 63;
    const long base = (long)bh << 18;               // bh * 2048 * 128
    const int qt = qg * 8 + w;
    const int q0 = qt * 32;
    const int tiles_w = qt + 1;
    const int NT = qg * 8 + 8;
    const float scale = 0.08838834764831845f;       // 1/sqrt(128)

    bf8 qf[2][4];
#pragma unroll
    for (int m = 0; m < 2; m++)
#pragma unroll
        for (int kb = 0; kb < 4; kb++)
            qf[m][kb] = *(const bf8*)(Qb + base + (long)(q0 + m * 16 + la) * 128 + kb * 32 + lb * 8);

    f4v o[2][8];
#pragma unroll
    for (int m = 0; m < 2; m++)
#pragma unroll
        for (int n = 0; n < 8; n++) o[m][n] = (f4v){0.f, 0.f, 0.f, 0.f};
    float lst[2][4];
#pragma unroll
    for (int m = 0; m < 2; m++)
#pragma unroll
        for (int i = 0; i < 4; i++) lst[m][i] = 0.f;

    char* Pb = (char*)(Pl[w]);

    const int ko = tid * 16;
    const int kr = ko >> 8, kc = (ko & 255) ^ ((kr & 7) << 4);
    const int vo = tid * 16;
    const int vR = vo >> 7, vc = (vo & 127) ^ ((vR & 7) << 4);
    const int vd = 2 * vR + (vc >> 6), vt = (vc & 63) >> 1;

#define STAGE(buf, jt_) do {                                                        \
        const int kv0_ = (jt_) * 32;                                               \
        __builtin_amdgcn_global_load_lds(                                          \
            GLB(Kb + base + (long)(kv0_ + kr) * 128 + (kc >> 1)),                  \
            LDS((u16*)Ks[buf] + tid * 8), 16, 0, 0);                               \
        __builtin_amdgcn_global_load_lds(                                          \
            GLB(Vt + base + ((long)vd << 11) + kv0_ + vt),                         \
            LDS((u16*)Vs[buf] + tid * 8), 16, 0, 0);                               \
    } while (0)

    STAGE(0, 0);

    for (int jt = 0; jt < NT; ++jt) {
        const int buf = jt & 1;
        __syncthreads();
        if (jt + 1 < NT) STAGE(buf ^ 1, jt + 1);

        if (jt < tiles_w) {
            const char* KsB = (const char*)Ks[buf];
            const char* VsB = (const char*)Vs[buf];

            f4v s[2][2];
            s[0][0] = s[0][1] = s[1][0] = s[1][1] = (f4v){0.f, 0.f, 0.f, 0.f};
#pragma unroll
            for (int n = 0; n < 2; n++) {
                const int row = n * 16 + la;
#pragma unroll
                for (int kb = 0; kb < 4; kb++) {
                    bf8 kf = *(const bf8*)(KsB + row * 256 + ((kb * 64 + lb * 16) ^ ((row & 7) << 4)));
                    s[0][n] = __builtin_amdgcn_mfma_f32_16x16x32_bf16(qf[0][kb], kf, s[0][n], 0, 0, 0);
                    s[1][n] = __builtin_amdgcn_mfma_f32_16x16x32_bf16(qf[1][kb], kf, s[1][n], 0, 0, 0);
                }
            }

            bf8 vf[8];
#pragma unroll
            for (int nO = 0; nO < 8; nO++) {
                const int R = nO * 8 + (la >> 1);
                vf[nO] = *(const bf8*)(VsB + R * 128 + (((la & 1) * 64 + lb * 16) ^ ((R & 7) << 4)));
            }

            const bool diag = (jt == qt);
            float p[2][2][4];
#pragma unroll
            for (int m = 0; m < 2; m++)
#pragma unroll
                for (int n = 0; n < 2; n++)
#pragma unroll
                    for (int i = 0; i < 4; i++) {
                        float v = __expf(fmaf(s[m][n][i], scale, -8.0f));
                        if (diag && (n * 16 + la) > (m * 16 + lb * 4 + i)) v = 0.f;
                        p[m][n][i] = v;
                        lst[m][i] += v;
                    }

#pragma unroll
            for (int m = 0; m < 2; m++)
#pragma unroll
                for (int n = 0; n < 2; n++)
#pragma unroll
                    for (int i = 0; i < 4; i++) {
                        const int row = m * 16 + lb * 4 + i;
                        const int colb = (n * 16 + la) * 2;
                        *(u16*)(Pb + row * 64 + (colb ^ ((row & 3) << 4))) = f2b(p[m][n][i]);
                    }
            bf8 pa[2];
#pragma unroll
            for (int am = 0; am < 2; am++) {
                const int row = am * 16 + la;
                pa[am] = *(const bf8*)(Pb + row * 64 + ((lb * 16) ^ ((row & 3) << 4)));
            }
#pragma unroll
            for (int nO = 0; nO < 8; nO++) {
                o[0][nO] = __builtin_amdgcn_mfma_f32_16x16x32_bf16(pa[0], vf[nO], o[0][nO], 0, 0, 0);
                o[1][nO] = __builtin_amdgcn_mfma_f32_16x16x32_bf16(pa[1], vf[nO], o[1][nO], 0, 0, 0);
            }
        }
        __syncthreads();
    }
#undef STAGE

    float linv[2][4];
#pragma unroll
    for (int m = 0; m < 2; m++)
#pragma unroll
        for (int i = 0; i < 4; i++) {
            float l = lst[m][i];
            l += __shfl_xor(l, 1);
            l += __shfl_xor(l, 2);
            l += __shfl_xor(l, 4);
            l += __shfl_xor(l, 8);
            linv[m][i] = 1.0f / l;
        }

    const int b = bh >> 4, h = bh & 15;
#pragma unroll
    for (int m = 0; m < 2; m++)
#pragma unroll
        for (int nO = 0; nO < 8; nO++)
#pragma unroll
            for (int i = 0; i < 4; i++) {
                const int row = q0 + m * 16 + lb * 4 + i;
                const int d = nO * 16 + la;
                Ob[((long)(b * 2048 + row) << 11) + h * 128 + d] = f2b(o[m][nO][i] * linv[m][i]);
            }
}

extern "C" void kernel_launch(void* const* d_in, const int* in_sizes, int n_in,
                              void* d_out, int out_size, void* d_ws, size_t ws_size,
                              hipStream_t stream)
{
    const float* X    = (const float*)d_in[0];
    const int*   pos  = (const int*)d_in[1];
    const float* Wqkv = (const float*)d_in[2];
    const float* Wo   = (const float*)d_in[3];
    float* out = (float*)d_out;

    char* ws = (char*)d_ws;
    u16* Xb    = (u16*)(ws + 0);          // 8192x2048 bf16   (32 MiB)
    u16* Wqkvb = (u16*)(ws + 33554432);   // 6144x2048 bf16   (24 MiB)
    u16* Wob   = (u16*)(ws + 58720256);   // 2048x2048 bf16   ( 8 MiB)
    u16* Qb    = (u16*)(ws + 67108864);   // [bh][t][128] bf16 (32 MiB)
    u16* Kb    = (u16*)(ws + 100663296);  // [bh][t][128]
    u16* Vt    = (u16*)(ws + 134217728);  // [bh][128][t]  (transposed)
    u16* Ob    = (u16*)(ws + 167772160);  // [b][t][2048] bf16

    k_conv<<<16384, 256, 0, stream>>>(X, Xb, 4194304);
    k_conv<<<12288, 256, 0, stream>>>(Wqkv, Wqkvb, 3145728);
    k_conv<<<4096, 256, 0, stream>>>(Wo, Wob, 1048576);
    // GEMM1: M=8192 N=6144 K=2048 -> grid 24x32 = 768 blocks (768%8==0)
    k_gemm_bt<0><<<768, 512, 131072, stream>>>(Xb, Wqkvb, 2048, 6144, 24, Qb, Kb, Vt, nullptr);
    k_rope<<<65536, 256, 0, stream>>>(Qb, Kb, pos);
    k_attn<<<512, 512, 0, stream>>>(Qb, Kb, Vt, Ob);
    // GEMM2: M=8192 N=2048 K=2048 -> grid 8x32 = 256 blocks
    k_gemm_bt<1><<<256, 512, 131072, stream>>>(Ob, Wob, 2048, 2048, 8, nullptr, nullptr, nullptr, out);
}

// Round 5
// 486.715 us; speedup vs baseline: 2.0961x; 1.0005x over previous
//
#include <hip/hip_runtime.h>

typedef unsigned short u16;
typedef __attribute__((ext_vector_type(8))) short s8v;
typedef __attribute__((ext_vector_type(8))) __bf16 bf8;
typedef __attribute__((ext_vector_type(4))) float f4v;

#define GLB(p) ((const __attribute__((address_space(1))) void*)(p))
#define LDS(p) ((__attribute__((address_space(3))) void*)(p))

static __device__ __forceinline__ float b2f(u16 u) {
    union { unsigned int i; float f; } v; v.i = ((unsigned int)u) << 16; return v.f;
}
static __device__ __forceinline__ u16 f2b(float f) {
    union { float f; unsigned int i; } v; v.f = f;
    v.i += 0x7fffu + ((v.i >> 16) & 1u);   // RNE
    return (u16)(v.i >> 16);
}

// ---------------- f32 -> bf16 convert, 4 elems/thread ----------------
__global__ __launch_bounds__(256) void k_conv(const float* __restrict__ in,
                                              u16* __restrict__ out, int n4) {
    int i = blockIdx.x * 256 + threadIdx.x;
    if (i >= n4) return;
    float4 v = ((const float4*)in)[i];
    union { u16 u[4]; unsigned long long ll; } o;
    o.u[0] = f2b(v.x); o.u[1] = f2b(v.y); o.u[2] = f2b(v.z); o.u[3] = f2b(v.w);
    ((unsigned long long*)out)[i] = o.ll;
}

// ============ C = A(MxK) * B(NxK)^T, 256x256 tile, BK=64, 8 waves ============
// 8-phase-style schedule: 4 fine phases per K-tile {ds_read subtile | stage |
// bar | 16 MFMA | bar}, burst-stage next tile at p0, counted vmcnt(6) at p3
// (never drain-0 in loop). 2 LDS dbufs x (A 32KB + B 32KB). XOR swizzle
// g^(row&7) on 8x16B granules per 128B row; inverse swizzle on staging source.
// MODE 0: scatter bf16 into Q/K head-major [bh][t][128], V transposed [bh][128][t]
// MODE 1: write f32 row-major C (M x N)
template<int MODE>
__global__ __launch_bounds__(512, 2) void k_gemm_bt(
    const u16* __restrict__ A, const u16* __restrict__ B,
    int K, int N, int gx,
    u16* __restrict__ Qb, u16* __restrict__ Kb, u16* __restrict__ Vt,
    float* __restrict__ Cf)
{
    extern __shared__ __align__(16) u16 Ls[];   // 2 bufs x 64KB = 128 KB

    const int t    = threadIdx.x;
    const int lane = t & 63;
    const int wid  = t >> 6;
    const int wm = wid >> 2, wn = wid & 3;       // 2x4 wave grid; per-wave 128x64 out
    const int la = lane & 15, lb = lane >> 4;

    // XCD-bijective block swizzle (grid % 8 == 0)
    const int bid = (int)blockIdx.x;
    const int id2 = (bid & 7) * ((int)gridDim.x >> 3) + (bid >> 3);
    const int bx = id2 % gx, by = id2 / gx;
    const long arow0 = (long)by * 256;
    const long brow0 = (long)bx * 256;

    // ---- staging: linear LDS dest, inverse-swizzled global source ----
    // half-buffer = 128 rows x 64 k (16KB). granule G = l*512 + t (16B each):
    // row = G>>3, slot = G&7 holds global k-granule g = slot ^ (row&7).
    const int sr = t >> 3;                       // row (load0); load1 = sr+64
    const int sg = (t & 7) ^ (sr & 7);           // global k-granule
    const u16* Asrc = A + (arow0 + sr) * (long)K + sg * 8;
    const u16* Bsrc = B + (brow0 + sr) * (long)K + sg * 8;
    const long K64 = 64 * (long)K, K128 = 128 * (long)K;
    u16* ldst = Ls + t * 8;
    // LDS u16 offsets: dbuf q: q*32768; op: +16384 for B; half h: +8192

#define STG(q_, op_, h_, kt_) do {                                              \
        const u16* s_ = ((op_) ? Bsrc : Asrc) + (h_) * K128 + (long)(kt_) * 64; \
        u16* d_ = ldst + (q_) * 32768 + (op_) * 16384 + (h_) * 4096 * 2;        \
        __builtin_amdgcn_global_load_lds(GLB(s_),       LDS(d_),        16, 0, 0); \
        __builtin_amdgcn_global_load_lds(GLB(s_ + K64), LDS(d_ + 4096), 16, 0, 0); \
    } while (0)
#define BAR() asm volatile("s_barrier" ::: "memory")
#define VM6() asm volatile("s_waitcnt vmcnt(6)" ::: "memory")
#define RD(off) (*(const bf8*)(Ls + (off)))

    f4v acc[8][4];
#pragma unroll
    for (int m = 0; m < 8; m++)
#pragma unroll
        for (int n = 0; n < 4; n++) acc[m][n] = (f4v){0.f, 0.f, 0.f, 0.f};

    // fragment-read swizzled offsets (u16 units)
    const int r7 = la & 7;
    const int gA0 = (lb ^ r7) * 8;               // ks=0
    const int gA1 = ((lb ^ r7) ^ 4) * 8;         // ks=1
    const int aRow = wm * 8192 + la * 64;                          // + mi*1024
    const int bRow = 16384 + (wn >> 1) * 8192 + ((wn & 1) * 64 + la) * 64; // + ni*1024

    const int NKT = K >> 6;
    // prologue: stage tile 0 into dbuf 0, drain once, barrier
    STG(0, 0, 0, 0); STG(0, 0, 1, 0); STG(0, 1, 0, 0); STG(0, 1, 1, 0);
    asm volatile("s_waitcnt vmcnt(0)\n\ts_barrier" ::: "memory");

    for (int X = 0; X < NKT; ++X) {
        const int D = (X & 1) << 15;
        const int q = (X + 1) & 1;
        const int S = (X + 1 < NKT) ? X + 1 : NKT - 1;
        bf8 aR[4][2], b0[2][2], b1[2][2];

        // ---- p0: A-sub0 + B-sub0 reads, burst-stage tile X+1, MFMA Q(0,0) ----
#pragma unroll
        for (int mi = 0; mi < 4; mi++) {
            aR[mi][0] = RD(D + aRow + mi * 1024 + gA0);
            aR[mi][1] = RD(D + aRow + mi * 1024 + gA1);
        }
#pragma unroll
        for (int nl = 0; nl < 2; nl++) {
            b0[nl][0] = RD(D + bRow + nl * 1024 + gA0);
            b0[nl][1] = RD(D + bRow + nl * 1024 + gA1);
        }
        STG(q, 0, 0, S); STG(q, 0, 1, S); STG(q, 1, 0, S); STG(q, 1, 1, S);
        BAR();
        __builtin_amdgcn_s_setprio(1);
#pragma unroll
        for (int mi = 0; mi < 4; mi++)
#pragma unroll
            for (int nl = 0; nl < 2; nl++) {
                acc[mi][nl] = __builtin_amdgcn_mfma_f32_16x16x32_bf16(aR[mi][0], b0[nl][0], acc[mi][nl], 0, 0, 0);
                acc[mi][nl] = __builtin_amdgcn_mfma_f32_16x16x32_bf16(aR[mi][1], b0[nl][1], acc[mi][nl], 0, 0, 0);
            }
        __builtin_amdgcn_s_setprio(0);
        BAR();

        // ---- p1: B-sub1 reads, MFMA Q(0,1) ----
#pragma unroll
        for (int nl = 0; nl < 2; nl++) {
            b1[nl][0] = RD(D + bRow + (2 + nl) * 1024 + gA0);
            b1[nl][1] = RD(D + bRow + (2 + nl) * 1024 + gA1);
        }
        BAR();
        __builtin_amdgcn_s_setprio(1);
#pragma unroll
        for (int mi = 0; mi < 4; mi++)
#pragma unroll
            for (int nl = 0; nl < 2; nl++) {
                acc[mi][2 + nl] = __builtin_amdgcn_mfma_f32_16x16x32_bf16(aR[mi][0], b1[nl][0], acc[mi][2 + nl], 0, 0, 0);
                acc[mi][2 + nl] = __builtin_amdgcn_mfma_f32_16x16x32_bf16(aR[mi][1], b1[nl][1], acc[mi][2 + nl], 0, 0, 0);
            }
        __builtin_amdgcn_s_setprio(0);
        BAR();

        // ---- p2: A-sub1 reads (reuse aR), MFMA Q(1,1) ----
#pragma unroll
        for (int mi = 0; mi < 4; mi++) {
            aR[mi][0] = RD(D + aRow + (4 + mi) * 1024 + gA0);
            aR[mi][1] = RD(D + aRow + (4 + mi) * 1024 + gA1);
        }
        BAR();
        __builtin_amdgcn_s_setprio(1);
#pragma unroll
        for (int mi = 0; mi < 4; mi++)
#pragma unroll
            for (int nl = 0; nl < 2; nl++) {
                acc[4 + mi][2 + nl] = __builtin_amdgcn_mfma_f32_16x16x32_bf16(aR[mi][0], b1[nl][0], acc[4 + mi][2 + nl], 0, 0, 0);
                acc[4 + mi][2 + nl] = __builtin_amdgcn_mfma_f32_16x16x32_bf16(aR[mi][1], b1[nl][1], acc[4 + mi][2 + nl], 0, 0, 0);
            }
        __builtin_amdgcn_s_setprio(0);
        BAR();

        // ---- p3: counted vmcnt (tile X+1 burst: prev burst landed), MFMA Q(1,0) ----
        VM6();
        BAR();
        __builtin_amdgcn_s_setprio(1);
#pragma unroll
        for (int mi = 0; mi < 4; mi++)
#pragma unroll
            for (int nl = 0; nl < 2; nl++) {
                acc[4 + mi][nl] = __builtin_amdgcn_mfma_f32_16x16x32_bf16(aR[mi][0], b0[nl][0], acc[4 + mi][nl], 0, 0, 0);
                acc[4 + mi][nl] = __builtin_amdgcn_mfma_f32_16x16x32_bf16(aR[mi][1], b0[nl][1], acc[4 + mi][nl], 0, 0, 0);
            }
        __builtin_amdgcn_s_setprio(0);
        BAR();
    }
    asm volatile("s_waitcnt vmcnt(0)" ::: "memory");
#undef STG
#undef BAR
#undef VM6
#undef RD

#pragma unroll
    for (int mi = 0; mi < 8; mi++) {
#pragma unroll
        for (int ni = 0; ni < 4; ni++) {
            const long grow0 = arow0 + wm * 128 + mi * 16 + lb * 4;
            const int  gcol  = (int)brow0 + wn * 64 + ni * 16 + la;
#pragma unroll
            for (int i = 0; i < 4; i++) {
                const float v = acc[mi][ni][i];
                const long r = grow0 + i;
                if (MODE == 0) {
                    const int part = gcol >> 11;           // 0=Q 1=K 2=V
                    const int rem  = gcol & 2047;
                    const int head = rem >> 7, d = rem & 127;
                    const long bh = (r >> 11) * 16 + head;
                    const int tt = (int)(r & 2047);
                    if (part == 2) {
                        Vt[(bh << 18) + ((long)d << 11) + tt] = f2b(v);   // [bh][d][t]
                    } else {
                        u16* dst = (part == 0) ? Qb : Kb;
                        dst[((bh << 11) + tt) * 128 + d] = f2b(v);
                    }
                } else {
                    Cf[r * (long)N + gcol] = v;
                }
            }
        }
    }
}

// ---------------- RoPE in place on Q and K (head-major) ----------------
__global__ __launch_bounds__(256) void k_rope(u16* __restrict__ Qb, u16* __restrict__ Kb,
                                              const int* __restrict__ pos) {
    const int idx = blockIdx.x * 256 + threadIdx.x;   // 2 * 64 * 2048 * 64 threads
    const int j  = idx & 63;
    const int t  = (idx >> 6) & 2047;
    const int bh = (idx >> 17) & 63;
    u16* P = (idx >> 23) ? Kb : Qb;
    const long off = ((((long)bh << 11) + t) << 7) + 2 * j;
    unsigned int raw = *(unsigned int*)(P + off);
    float x1 = b2f((u16)(raw & 0xffffu));
    float x2 = b2f((u16)(raw >> 16));
    float invf = exp2f((float)j * -0.20762050593046014f);  // 10000^(-j/64)
    float ang = (float)pos[t] * invf;
    float sn, cs;
    sincosf(ang, &sn, &cs);
    unsigned int o = (unsigned int)f2b(x1 * cs - x2 * sn)
                   | ((unsigned int)f2b(x1 * sn + x2 * cs) << 16);
    *(unsigned int*)(P + off) = o;
}

// ---------------- causal flash attention, block-cooperative ----------------
__global__ __launch_bounds__(512) void k_attn(const u16* __restrict__ Qb,
                                              const u16* __restrict__ Kb,
                                              const u16* __restrict__ Vt,
                                              u16* __restrict__ Ob)
{
    __shared__ __align__(16) u16 Ks[2][32 * 128];   // 2 x 8KB, swizzled rows of 256B
    __shared__ __align__(16) u16 Vs[2][64 * 64];    // 2 x 8KB, row R = d-pair, 128B rows
    __shared__ __align__(16) u16 Pl[8][32 * 32];    // per-wave P buffer, 2KB each

    const int tid  = threadIdx.x;
    const int lane = tid & 63;
    const int w    = tid >> 6;
    const int la = lane & 15, lb = lane >> 4;
    const int qg = 7 - ((int)blockIdx.x >> 6);      // longest blocks dispatch first
    const int bh = blockIdx.x & 63;
    const long base = (long)bh << 18;               // bh * 2048 * 128
    const int qt = qg * 8 + w;
    const int q0 = qt * 32;
    const int tiles_w = qt + 1;
    const int NT = qg * 8 + 8;
    const float scale = 0.08838834764831845f;       // 1/sqrt(128)

    bf8 qf[2][4];
#pragma unroll
    for (int m = 0; m < 2; m++)
#pragma unroll
        for (int kb = 0; kb < 4; kb++)
            qf[m][kb] = *(const bf8*)(Qb + base + (long)(q0 + m * 16 + la) * 128 + kb * 32 + lb * 8);

    f4v o[2][8];
#pragma unroll
    for (int m = 0; m < 2; m++)
#pragma unroll
        for (int n = 0; n < 8; n++) o[m][n] = (f4v){0.f, 0.f, 0.f, 0.f};
    float lst[2][4];
#pragma unroll
    for (int m = 0; m < 2; m++)
#pragma unroll
        for (int i = 0; i < 4; i++) lst[m][i] = 0.f;

    char* Pb = (char*)(Pl[w]);

    const int ko = tid * 16;
    const int kr = ko >> 8, kc = (ko & 255) ^ ((kr & 7) << 4);
    const int vo = tid * 16;
    const int vR = vo >> 7, vc = (vo & 127) ^ ((vR & 7) << 4);
    const int vd = 2 * vR + (vc >> 6), vt = (vc & 63) >> 1;

#define STAGE(buf, jt_) do {                                                        \
        const int kv0_ = (jt_) * 32;                                               \
        __builtin_amdgcn_global_load_lds(                                          \
            GLB(Kb + base + (long)(kv0_ + kr) * 128 + (kc >> 1)),                  \
            LDS((u16*)Ks[buf] + tid * 8), 16, 0, 0);                               \
        __builtin_amdgcn_global_load_lds(                                          \
            GLB(Vt + base + ((long)vd << 11) + kv0_ + vt),                         \
            LDS((u16*)Vs[buf] + tid * 8), 16, 0, 0);                               \
    } while (0)

    STAGE(0, 0);

    for (int jt = 0; jt < NT; ++jt) {
        const int buf = jt & 1;
        __syncthreads();
        if (jt + 1 < NT) STAGE(buf ^ 1, jt + 1);

        if (jt < tiles_w) {
            const char* KsB = (const char*)Ks[buf];
            const char* VsB = (const char*)Vs[buf];

            f4v s[2][2];
            s[0][0] = s[0][1] = s[1][0] = s[1][1] = (f4v){0.f, 0.f, 0.f, 0.f};
#pragma unroll
            for (int n = 0; n < 2; n++) {
                const int row = n * 16 + la;
#pragma unroll
                for (int kb = 0; kb < 4; kb++) {
                    bf8 kf = *(const bf8*)(KsB + row * 256 + ((kb * 64 + lb * 16) ^ ((row & 7) << 4)));
                    s[0][n] = __builtin_amdgcn_mfma_f32_16x16x32_bf16(qf[0][kb], kf, s[0][n], 0, 0, 0);
                    s[1][n] = __builtin_amdgcn_mfma_f32_16x16x32_bf16(qf[1][kb], kf, s[1][n], 0, 0, 0);
                }
            }

            bf8 vf[8];
#pragma unroll
            for (int nO = 0; nO < 8; nO++) {
                const int R = nO * 8 + (la >> 1);
                vf[nO] = *(const bf8*)(VsB + R * 128 + (((la & 1) * 64 + lb * 16) ^ ((R & 7) << 4)));
            }

            const bool diag = (jt == qt);
            float p[2][2][4];
#pragma unroll
            for (int m = 0; m < 2; m++)
#pragma unroll
                for (int n = 0; n < 2; n++)
#pragma unroll
                    for (int i = 0; i < 4; i++) {
                        float v = __expf(fmaf(s[m][n][i], scale, -8.0f));
                        if (diag && (n * 16 + la) > (m * 16 + lb * 4 + i)) v = 0.f;
                        p[m][n][i] = v;
                        lst[m][i] += v;
                    }

#pragma unroll
            for (int m = 0; m < 2; m++)
#pragma unroll
                for (int n = 0; n < 2; n++)
#pragma unroll
                    for (int i = 0; i < 4; i++) {
                        const int row = m * 16 + lb * 4 + i;
                        const int colb = (n * 16 + la) * 2;
                        *(u16*)(Pb + row * 64 + (colb ^ ((row & 3) << 4))) = f2b(p[m][n][i]);
                    }
            bf8 pa[2];
#pragma unroll
            for (int am = 0; am < 2; am++) {
                const int row = am * 16 + la;
                pa[am] = *(const bf8*)(Pb + row * 64 + ((lb * 16) ^ ((row & 3) << 4)));
            }
#pragma unroll
            for (int nO = 0; nO < 8; nO++) {
                o[0][nO] = __builtin_amdgcn_mfma_f32_16x16x32_bf16(pa[0], vf[nO], o[0][nO], 0, 0, 0);
                o[1][nO] = __builtin_amdgcn_mfma_f32_16x16x32_bf16(pa[1], vf[nO], o[1][nO], 0, 0, 0);
            }
        }
        __syncthreads();
    }
#undef STAGE

    float linv[2][4];
#pragma unroll
    for (int m = 0; m < 2; m++)
#pragma unroll
        for (int i = 0; i < 4; i++) {
            float l = lst[m][i];
            l += __shfl_xor(l, 1);
            l += __shfl_xor(l, 2);
            l += __shfl_xor(l, 4);
            l += __shfl_xor(l, 8);
            linv[m][i] = 1.0f / l;
        }

    const int b = bh >> 4, h = bh & 15;
#pragma unroll
    for (int m = 0; m < 2; m++)
#pragma unroll
        for (int nO = 0; nO < 8; nO++)
#pragma unroll
            for (int i = 0; i < 4; i++) {
                const int row = q0 + m * 16 + lb * 4 + i;
                const int d = nO * 16 + la;
                Ob[((long)(b * 2048 + row) << 11) + h * 128 + d] = f2b(o[m][nO][i] * linv[m][i]);
            }
}

extern "C" void kernel_launch(void* const* d_in, const int* in_sizes, int n_in,
                              void* d_out, int out_size, void* d_ws, size_t ws_size,
                              hipStream_t stream)
{
    const float* X    = (const float*)d_in[0];
    const int*   pos  = (const int*)d_in[1];
    const float* Wqkv = (const float*)d_in[2];
    const float* Wo   = (const float*)d_in[3];
    float* out = (float*)d_out;

    char* ws = (char*)d_ws;
    u16* Xb    = (u16*)(ws + 0);          // 8192x2048 bf16   (32 MiB)
    u16* Wqkvb = (u16*)(ws + 33554432);   // 6144x2048 bf16   (24 MiB)
    u16* Wob   = (u16*)(ws + 58720256);   // 2048x2048 bf16   ( 8 MiB)
    u16* Qb    = (u16*)(ws + 67108864);   // [bh][t][128] bf16 (32 MiB)
    u16* Kb    = (u16*)(ws + 100663296);  // [bh][t][128]
    u16* Vt    = (u16*)(ws + 134217728);  // [bh][128][t]  (transposed)
    u16* Ob    = (u16*)(ws + 167772160);  // [b][t][2048] bf16

    k_conv<<<16384, 256, 0, stream>>>(X, Xb, 4194304);
    k_conv<<<12288, 256, 0, stream>>>(Wqkv, Wqkvb, 3145728);
    k_conv<<<4096, 256, 0, stream>>>(Wo, Wob, 1048576);
    // GEMM1: M=8192 N=6144 K=2048 -> grid 24x32 = 768 blocks (768%8==0)
    k_gemm_bt<0><<<768, 512, 131072, stream>>>(Xb, Wqkvb, 2048, 6144, 24, Qb, Kb, Vt, nullptr);
    k_rope<<<65536, 256, 0, stream>>>(Qb, Kb, pos);
    k_attn<<<512, 512, 0, stream>>>(Qb, Kb, Vt, Ob);
    // GEMM2: M=8192 N=2048 K=2048 -> grid 8x32 = 256 blocks
    k_gemm_bt<1><<<256, 512, 131072, stream>>>(Ob, Wob, 2048, 2048, 8, nullptr, nullptr, nullptr, out);
}

// Round 6
// 436.221 us; speedup vs baseline: 2.3387x; 1.1158x over previous
//
#include <hip/hip_runtime.h>

typedef unsigned short u16;
typedef __attribute__((ext_vector_type(8))) short s8v;
typedef __attribute__((ext_vector_type(8))) __bf16 bf8;
typedef __attribute__((ext_vector_type(4))) float f4v;

#define GLB(p) ((const __attribute__((address_space(1))) void*)(p))
#define LDS(p) ((__attribute__((address_space(3))) void*)(p))

static __device__ __forceinline__ float b2f(u16 u) {
    union { unsigned int i; float f; } v; v.i = ((unsigned int)u) << 16; return v.f;
}
static __device__ __forceinline__ u16 f2b(float f) {
    union { float f; unsigned int i; } v; v.f = f;
    v.i += 0x7fffu + ((v.i >> 16) & 1u);   // RNE
    return (u16)(v.i >> 16);
}

// ---------------- f32 -> bf16 convert, 4 elems/thread ----------------
__global__ __launch_bounds__(256) void k_conv(const float* __restrict__ in,
                                              u16* __restrict__ out, int n4) {
    int i = blockIdx.x * 256 + threadIdx.x;
    if (i >= n4) return;
    float4 v = ((const float4*)in)[i];
    union { u16 u[4]; unsigned long long ll; } o;
    o.u[0] = f2b(v.x); o.u[1] = f2b(v.y); o.u[2] = f2b(v.z); o.u[3] = f2b(v.w);
    ((unsigned long long*)out)[i] = o.ll;
}

// ============ C = A(MxK) * B(NxK)^T, 256x256 tile, BK=64, 8 waves ============
// ONE barrier per phase (at MFMA start): phase k+1's ds_reads issue immediately
// after phase k's MFMA cluster and execute DURING its drain -> LDS||MFMA overlap.
// Burst-stage next K-tile at p0; vmcnt(0) only at p3 (loads aged 3 phases, ~free).
// XOR swizzle g^(row&7) on 16B granules; inverse swizzle on staging source.
// MODE 0: coalesced epilogue via padded-LDS transpose into Q/K [bh][t][128] and
//         V transposed [bh][128][t].   MODE 1: f32 row-major C.
template<int MODE>
__global__ __launch_bounds__(512, 2) void k_gemm_bt(
    const u16* __restrict__ A, const u16* __restrict__ B,
    int K, int N, int gx,
    u16* __restrict__ Qb, u16* __restrict__ Kb, u16* __restrict__ Vt,
    float* __restrict__ Cf)
{
    extern __shared__ __align__(16) u16 Ls[];   // 2 dbufs x 64KB; epilogue reuses as 256x264

    const int t    = threadIdx.x;
    const int lane = t & 63;
    const int wid  = t >> 6;
    const int wm = wid >> 2, wn = wid & 3;       // 2x4 wave grid; per-wave 128x64 out
    const int la = lane & 15, lb = lane >> 4;

    // XCD-bijective block swizzle (grid % 8 == 0)
    const int bid = (int)blockIdx.x;
    const int id2 = (bid & 7) * ((int)gridDim.x >> 3) + (bid >> 3);
    const int bx = id2 % gx, by = id2 / gx;
    const long arow0 = (long)by * 256;
    const long brow0 = (long)bx * 256;

    // staging: linear LDS dest, inverse-swizzled global source
    const int sr = t >> 3;                       // row in half (0..63); +64 for 2nd inst
    const int sg = (t & 7) ^ (sr & 7);           // global k-granule (16B)
    const u16* Asrc = A + (arow0 + sr) * (long)K + sg * 8;
    const u16* Bsrc = B + (brow0 + sr) * (long)K + sg * 8;
    const long K64 = 64 * (long)K, K128 = 128 * (long)K;
    u16* ldst = Ls + t * 8;

#define STG(q_, op_, h_, kt_) do {                                              \
        const u16* s_ = ((op_) ? Bsrc : Asrc) + (h_) * K128 + (long)(kt_) * 64; \
        u16* d_ = ldst + (q_) * 32768 + (op_) * 16384 + (h_) * 8192;            \
        __builtin_amdgcn_global_load_lds(GLB(s_),       LDS(d_),        16, 0, 0); \
        __builtin_amdgcn_global_load_lds(GLB(s_ + K64), LDS(d_ + 4096), 16, 0, 0); \
    } while (0)
#define RD(off) (*(const bf8*)(Ls + (off)))

    f4v acc[8][4];
#pragma unroll
    for (int m = 0; m < 8; m++)
#pragma unroll
        for (int n = 0; n < 4; n++) acc[m][n] = (f4v){0.f, 0.f, 0.f, 0.f};

    // fragment-read swizzled offsets (u16 units)
    const int r7 = la & 7;
    const int gA0 = (lb ^ r7) * 8;               // ks=0 (granules 0..3)
    const int gA1 = ((lb ^ r7) ^ 4) * 8;         // ks=1 (granules 4..7)
    const int aRow = wm * 8192 + la * 64;                                   // + mi*1024
    const int bRow = 16384 + (wn >> 1) * 8192 + ((wn & 1) * 64 + la) * 64;  // + ni*1024

    const int NKT = K >> 6;
    STG(0, 0, 0, 0); STG(0, 0, 1, 0); STG(0, 1, 0, 0); STG(0, 1, 1, 0);
    asm volatile("s_waitcnt vmcnt(0)" ::: "memory");
    __builtin_amdgcn_s_barrier();

    for (int X = 0; X < NKT; ++X) {
        const int D = (X & 1) << 15;
        const int q = (X + 1) & 1;
        const int S = (X + 1 < NKT) ? X + 1 : NKT - 1;
        bf8 aR[4][2], b0[2][2], b1[2][2];

        // p0: A-sub0 + B-sub0 reads, burst-stage tile X+1 | bar | MFMA Q(0,0)
#pragma unroll
        for (int mi = 0; mi < 4; mi++) {
            aR[mi][0] = RD(D + aRow + mi * 1024 + gA0);
            aR[mi][1] = RD(D + aRow + mi * 1024 + gA1);
        }
#pragma unroll
        for (int nl = 0; nl < 2; nl++) {
            b0[nl][0] = RD(D + bRow + nl * 1024 + gA0);
            b0[nl][1] = RD(D + bRow + nl * 1024 + gA1);
        }
        STG(q, 0, 0, S); STG(q, 0, 1, S); STG(q, 1, 0, S); STG(q, 1, 1, S);
        __builtin_amdgcn_s_barrier();
        __builtin_amdgcn_s_setprio(1);
#pragma unroll
        for (int mi = 0; mi < 4; mi++)
#pragma unroll
            for (int nl = 0; nl < 2; nl++) {
                acc[mi][nl] = __builtin_amdgcn_mfma_f32_16x16x32_bf16(aR[mi][0], b0[nl][0], acc[mi][nl], 0, 0, 0);
                acc[mi][nl] = __builtin_amdgcn_mfma_f32_16x16x32_bf16(aR[mi][1], b0[nl][1], acc[mi][nl], 0, 0, 0);
            }
        __builtin_amdgcn_s_setprio(0);

        // p1: B-sub1 reads | bar | MFMA Q(0,1)
#pragma unroll
        for (int nl = 0; nl < 2; nl++) {
            b1[nl][0] = RD(D + bRow + (2 + nl) * 1024 + gA0);
            b1[nl][1] = RD(D + bRow + (2 + nl) * 1024 + gA1);
        }
        __builtin_amdgcn_s_barrier();
        __builtin_amdgcn_s_setprio(1);
#pragma unroll
        for (int mi = 0; mi < 4; mi++)
#pragma unroll
            for (int nl = 0; nl < 2; nl++) {
                acc[mi][2 + nl] = __builtin_amdgcn_mfma_f32_16x16x32_bf16(aR[mi][0], b1[nl][0], acc[mi][2 + nl], 0, 0, 0);
                acc[mi][2 + nl] = __builtin_amdgcn_mfma_f32_16x16x32_bf16(aR[mi][1], b1[nl][1], acc[mi][2 + nl], 0, 0, 0);
            }
        __builtin_amdgcn_s_setprio(0);

        // p2: A-sub1 reads | bar | MFMA Q(1,1)
#pragma unroll
        for (int mi = 0; mi < 4; mi++) {
            aR[mi][0] = RD(D + aRow + (4 + mi) * 1024 + gA0);
            aR[mi][1] = RD(D + aRow + (4 + mi) * 1024 + gA1);
        }
        __builtin_amdgcn_s_barrier();
        __builtin_amdgcn_s_setprio(1);
#pragma unroll
        for (int mi = 0; mi < 4; mi++)
#pragma unroll
            for (int nl = 0; nl < 2; nl++) {
                acc[4 + mi][2 + nl] = __builtin_amdgcn_mfma_f32_16x16x32_bf16(aR[mi][0], b1[nl][0], acc[4 + mi][2 + nl], 0, 0, 0);
                acc[4 + mi][2 + nl] = __builtin_amdgcn_mfma_f32_16x16x32_bf16(aR[mi][1], b1[nl][1], acc[4 + mi][2 + nl], 0, 0, 0);
            }
        __builtin_amdgcn_s_setprio(0);

        // p3: drain staging (aged 3 phases, ~free) | bar | MFMA Q(1,0)
        asm volatile("s_waitcnt vmcnt(0)" ::: "memory");
        __builtin_amdgcn_s_barrier();
        __builtin_amdgcn_s_setprio(1);
#pragma unroll
        for (int mi = 0; mi < 4; mi++)
#pragma unroll
            for (int nl = 0; nl < 2; nl++) {
                acc[4 + mi][nl] = __builtin_amdgcn_mfma_f32_16x16x32_bf16(aR[mi][0], b0[nl][0], acc[4 + mi][nl], 0, 0, 0);
                acc[4 + mi][nl] = __builtin_amdgcn_mfma_f32_16x16x32_bf16(aR[mi][1], b0[nl][1], acc[4 + mi][nl], 0, 0, 0);
            }
        __builtin_amdgcn_s_setprio(0);
    }
#undef STG
#undef RD

    if (MODE == 1) {
#pragma unroll
        for (int mi = 0; mi < 8; mi++)
#pragma unroll
            for (int ni = 0; ni < 4; ni++) {
                const long grow0 = arow0 + wm * 128 + mi * 16 + lb * 4;
                const int  gcol  = (int)brow0 + wn * 64 + ni * 16 + la;
#pragma unroll
                for (int i = 0; i < 4; i++)
                    Cf[(grow0 + i) * (long)N + gcol] = acc[mi][ni][i];
            }
        return;
    }

    // ---- MODE 0 epilogue: transpose through padded LDS, coalesced stores ----
    __syncthreads();                 // K-loop done; reuse Ls as E[.. * 264]
    const int part = (int)(brow0 >> 11);         // 0=Q 1=K 2=V (tile within one part)
    const int colp = (int)brow0 & 2047;
    const int h0   = colp >> 7;                  // first head in tile (2 heads/tile)
    const int bidx = (int)(arow0 >> 11);         // batch (t-rows within one b)
    const int t0   = (int)arow0 & 2047;

    if (part == 2) {
        // E[dl*264 + tl] : dl = local d-col (0..255), tl = local t-row
#pragma unroll
        for (int mi = 0; mi < 8; mi++)
#pragma unroll
            for (int ni = 0; ni < 4; ni++) {
                const int tlb = wm * 128 + mi * 16 + lb * 4;
                const int dl  = wn * 64 + ni * 16 + la;
#pragma unroll
                for (int i2 = 0; i2 < 2; i2++) {
                    unsigned int pk = (unsigned int)f2b(acc[mi][ni][i2 * 2])
                                    | ((unsigned int)f2b(acc[mi][ni][i2 * 2 + 1]) << 16);
                    *(unsigned int*)(Ls + dl * 264 + tlb + i2 * 2) = pk;
                }
            }
        __syncthreads();
        const int w = wid;
#pragma unroll
        for (int j = 0; j < 16; j++) {
            const int dl = j * 16 + w * 2 + (lane >> 5);
            const int c  = lane & 31;
            bf8 v = *(const bf8*)(Ls + dl * 264 + c * 8);
            const long bh = (long)(bidx * 16 + h0 + (dl >> 7));
            *(bf8*)(Vt + (bh << 18) + ((long)(dl & 127) << 11) + t0 + c * 8) = v;
        }
    } else {
        u16* dst = (part == 0) ? Qb : Kb;
        // E[tl*264 + dl]
#pragma unroll
        for (int mi = 0; mi < 8; mi++)
#pragma unroll
            for (int ni = 0; ni < 4; ni++) {
                const int tlb = wm * 128 + mi * 16 + lb * 4;
                const int dl  = wn * 64 + ni * 16 + la;
#pragma unroll
                for (int i = 0; i < 4; i++)
                    Ls[(tlb + i) * 264 + dl] = f2b(acc[mi][ni][i]);
            }
        __syncthreads();
#pragma unroll
        for (int j = 0; j < 16; j++) {
            const int R  = j * 32 + (t >> 4);    // row-half index 0..511
            const int tl = R >> 1, hh = R & 1, c = t & 15;
            bf8 v = *(const bf8*)(Ls + tl * 264 + hh * 128 + c * 8);
            const long bh = (long)(bidx * 16 + h0 + hh);
            *(bf8*)(dst + ((bh << 11) + t0 + tl) * 128 + c * 8) = v;
        }
    }
}

// ---------------- RoPE in place on Q and K (head-major) ----------------
__global__ __launch_bounds__(256) void k_rope(u16* __restrict__ Qb, u16* __restrict__ Kb,
                                              const int* __restrict__ pos) {
    const int idx = blockIdx.x * 256 + threadIdx.x;   // 2 * 64 * 2048 * 64 threads
    const int j  = idx & 63;
    const int t  = (idx >> 6) & 2047;
    const int bh = (idx >> 17) & 63;
    u16* P = (idx >> 23) ? Kb : Qb;
    const long off = ((((long)bh << 11) + t) << 7) + 2 * j;
    unsigned int raw = *(unsigned int*)(P + off);
    float x1 = b2f((u16)(raw & 0xffffu));
    float x2 = b2f((u16)(raw >> 16));
    float invf = exp2f((float)j * -0.20762050593046014f);  // 10000^(-j/64)
    float ang = (float)pos[t] * invf;
    float sn, cs;
    sincosf(ang, &sn, &cs);
    unsigned int o = (unsigned int)f2b(x1 * cs - x2 * sn)
                   | ((unsigned int)f2b(x1 * sn + x2 * cs) << 16);
    *(unsigned int*)(P + off) = o;
}

// ---------------- causal flash attention, block-cooperative ----------------
__global__ __launch_bounds__(512) void k_attn(const u16* __restrict__ Qb,
                                              const u16* __restrict__ Kb,
                                              const u16* __restrict__ Vt,
                                              u16* __restrict__ Ob)
{
    __shared__ __align__(16) u16 Ks[2][32 * 128];
    __shared__ __align__(16) u16 Vs[2][64 * 64];
    __shared__ __align__(16) u16 Pl[8][32 * 32];

    const int tid  = threadIdx.x;
    const int lane = tid & 63;
    const int w    = tid >> 6;
    const int la = lane & 15, lb = lane >> 4;
    const int qg = 7 - ((int)blockIdx.x >> 6);
    const int bh = blockIdx.x & 63;
    const long base = (long)bh << 18;
    const int qt = qg * 8 + w;
    const int q0 = qt * 32;
    const int tiles_w = qt + 1;
    const int NT = qg * 8 + 8;
    const float scale = 0.08838834764831845f;

    bf8 qf[2][4];
#pragma unroll
    for (int m = 0; m < 2; m++)
#pragma unroll
        for (int kb = 0; kb < 4; kb++)
            qf[m][kb] = *(const bf8*)(Qb + base + (long)(q0 + m * 16 + la) * 128 + kb * 32 + lb * 8);

    f4v o[2][8];
#pragma unroll
    for (int m = 0; m < 2; m++)
#pragma unroll
        for (int n = 0; n < 8; n++) o[m][n] = (f4v){0.f, 0.f, 0.f, 0.f};
    float lst[2][4];
#pragma unroll
    for (int m = 0; m < 2; m++)
#pragma unroll
        for (int i = 0; i < 4; i++) lst[m][i] = 0.f;

    char* Pb = (char*)(Pl[w]);

    const int ko = tid * 16;
    const int kr = ko >> 8, kc = (ko & 255) ^ ((kr & 7) << 4);
    const int vo = tid * 16;
    const int vR = vo >> 7, vc = (vo & 127) ^ ((vR & 7) << 4);
    const int vd = 2 * vR + (vc >> 6), vt = (vc & 63) >> 1;

#define STAGE(buf, jt_) do {                                                        \
        const int kv0_ = (jt_) * 32;                                               \
        __builtin_amdgcn_global_load_lds(                                          \
            GLB(Kb + base + (long)(kv0_ + kr) * 128 + (kc >> 1)),                  \
            LDS((u16*)Ks[buf] + tid * 8), 16, 0, 0);                               \
        __builtin_amdgcn_global_load_lds(                                          \
            GLB(Vt + base + ((long)vd << 11) + kv0_ + vt),                         \
            LDS((u16*)Vs[buf] + tid * 8), 16, 0, 0);                               \
    } while (0)

    STAGE(0, 0);

    for (int jt = 0; jt < NT; ++jt) {
        const int buf = jt & 1;
        __syncthreads();
        if (jt + 1 < NT) STAGE(buf ^ 1, jt + 1);

        if (jt < tiles_w) {
            const char* KsB = (const char*)Ks[buf];
            const char* VsB = (const char*)Vs[buf];

            f4v s[2][2];
            s[0][0] = s[0][1] = s[1][0] = s[1][1] = (f4v){0.f, 0.f, 0.f, 0.f};
#pragma unroll
            for (int n = 0; n < 2; n++) {
                const int row = n * 16 + la;
#pragma unroll
                for (int kb = 0; kb < 4; kb++) {
                    bf8 kf = *(const bf8*)(KsB + row * 256 + ((kb * 64 + lb * 16) ^ ((row & 7) << 4)));
                    s[0][n] = __builtin_amdgcn_mfma_f32_16x16x32_bf16(qf[0][kb], kf, s[0][n], 0, 0, 0);
                    s[1][n] = __builtin_amdgcn_mfma_f32_16x16x32_bf16(qf[1][kb], kf, s[1][n], 0, 0, 0);
                }
            }

            bf8 vf[8];
#pragma unroll
            for (int nO = 0; nO < 8; nO++) {
                const int R = nO * 8 + (la >> 1);
                vf[nO] = *(const bf8*)(VsB + R * 128 + (((la & 1) * 64 + lb * 16) ^ ((R & 7) << 4)));
            }

            const bool diag = (jt == qt);
            float p[2][2][4];
#pragma unroll
            for (int m = 0; m < 2; m++)
#pragma unroll
                for (int n = 0; n < 2; n++)
#pragma unroll
                    for (int i = 0; i < 4; i++) {
                        float v = __expf(fmaf(s[m][n][i], scale, -8.0f));
                        if (diag && (n * 16 + la) > (m * 16 + lb * 4 + i)) v = 0.f;
                        p[m][n][i] = v;
                        lst[m][i] += v;
                    }

#pragma unroll
            for (int m = 0; m < 2; m++)
#pragma unroll
                for (int n = 0; n < 2; n++)
#pragma unroll
                    for (int i = 0; i < 4; i++) {
                        const int row = m * 16 + lb * 4 + i;
                        const int colb = (n * 16 + la) * 2;
                        *(u16*)(Pb + row * 64 + (colb ^ ((row & 3) << 4))) = f2b(p[m][n][i]);
                    }
            bf8 pa[2];
#pragma unroll
            for (int am = 0; am < 2; am++) {
                const int row = am * 16 + la;
                pa[am] = *(const bf8*)(Pb + row * 64 + ((lb * 16) ^ ((row & 3) << 4)));
            }
#pragma unroll
            for (int nO = 0; nO < 8; nO++) {
                o[0][nO] = __builtin_amdgcn_mfma_f32_16x16x32_bf16(pa[0], vf[nO], o[0][nO], 0, 0, 0);
                o[1][nO] = __builtin_amdgcn_mfma_f32_16x16x32_bf16(pa[1], vf[nO], o[1][nO], 0, 0, 0);
            }
        }
        __syncthreads();
    }
#undef STAGE

    float linv[2][4];
#pragma unroll
    for (int m = 0; m < 2; m++)
#pragma unroll
        for (int i = 0; i < 4; i++) {
            float l = lst[m][i];
            l += __shfl_xor(l, 1);
            l += __shfl_xor(l, 2);
            l += __shfl_xor(l, 4);
            l += __shfl_xor(l, 8);
            linv[m][i] = 1.0f / l;
        }

    const int b = bh >> 4, h = bh & 15;
#pragma unroll
    for (int m = 0; m < 2; m++)
#pragma unroll
        for (int nO = 0; nO < 8; nO++)
#pragma unroll
            for (int i = 0; i < 4; i++) {
                const int row = q0 + m * 16 + lb * 4 + i;
                const int d = nO * 16 + la;
                Ob[((long)(b * 2048 + row) << 11) + h * 128 + d] = f2b(o[m][nO][i] * linv[m][i]);
            }
}

extern "C" void kernel_launch(void* const* d_in, const int* in_sizes, int n_in,
                              void* d_out, int out_size, void* d_ws, size_t ws_size,
                              hipStream_t stream)
{
    const float* X    = (const float*)d_in[0];
    const int*   pos  = (const int*)d_in[1];
    const float* Wqkv = (const float*)d_in[2];
    const float* Wo   = (const float*)d_in[3];
    float* out = (float*)d_out;

    char* ws = (char*)d_ws;
    u16* Xb    = (u16*)(ws + 0);          // 8192x2048 bf16   (32 MiB)
    u16* Wqkvb = (u16*)(ws + 33554432);   // 6144x2048 bf16   (24 MiB)
    u16* Wob   = (u16*)(ws + 58720256);   // 2048x2048 bf16   ( 8 MiB)
    u16* Qb    = (u16*)(ws + 67108864);   // [bh][t][128] bf16 (32 MiB)
    u16* Kb    = (u16*)(ws + 100663296);  // [bh][t][128]
    u16* Vt    = (u16*)(ws + 134217728);  // [bh][128][t]  (transposed)
    u16* Ob    = (u16*)(ws + 167772160);  // [b][t][2048] bf16

    k_conv<<<16384, 256, 0, stream>>>(X, Xb, 4194304);
    k_conv<<<12288, 256, 0, stream>>>(Wqkv, Wqkvb, 3145728);
    k_conv<<<4096, 256, 0, stream>>>(Wo, Wob, 1048576);
    // GEMM1: M=8192 N=6144 K=2048 -> grid 24x32 = 768 blocks
    k_gemm_bt<0><<<768, 512, 139392, stream>>>(Xb, Wqkvb, 2048, 6144, 24, Qb, Kb, Vt, nullptr);
    k_rope<<<65536, 256, 0, stream>>>(Qb, Kb, pos);
    k_attn<<<512, 512, 0, stream>>>(Qb, Kb, Vt, Ob);
    // GEMM2: M=8192 N=2048 K=2048 -> grid 8x32 = 256 blocks
    k_gemm_bt<1><<<256, 512, 139392, stream>>>(Ob, Wob, 2048, 2048, 8, nullptr, nullptr, nullptr, out);
}